// Round 1
// baseline (4158.561 us; speedup 1.0000x reference)
//
#include <hip/hip_runtime.h>

#define NN 50000
#define NE 800000
#define DIM 128
#define NC 32
#define BN_EPS 1e-5f
#define SELU_ALPHA 1.6732632423543772f
#define SELU_SCALE 1.0507009873554805f

// ---------- edge dtype detection + conversion ----------
// If edge_index arrived as int64 (little-endian, values < 50000), every odd
// int32 word is 0. For int32 data, P(first 64 odd words all zero) ~ (1/5e4)^64.
__global__ void k_detect(const int* __restrict__ raw, int* __restrict__ flag) {
    int v = raw[2 * threadIdx.x + 1];
    unsigned long long b = __ballot(v == 0);
    if (threadIdx.x == 0) *flag = (b == 0xFFFFFFFFFFFFFFFFULL) ? 1 : 0;
}

__global__ void k_convert(const void* __restrict__ raw, const int* __restrict__ flag,
                          int* __restrict__ es) {
    int f = *flag;
    int i = blockIdx.x * blockDim.x + threadIdx.x;
    if (i < 2 * NE) {
        es[i] = f ? (int)((const long long*)raw)[i] : ((const int*)raw)[i];
    }
}

__global__ void k_zero(float* __restrict__ p, int n) {
    int i = blockIdx.x * blockDim.x + threadIdx.x;
    if (i < n) p[i] = 0.f;
}

// ---------- aggregation: out = in (copy), then scatter-add over edges ----------
__global__ void k_copy(const float4* __restrict__ in, float4* __restrict__ out, int n4) {
    int i = blockIdx.x * blockDim.x + threadIdx.x;
    if (i < n4) out[i] = in[i];
}

__global__ void k_scatter(const float* __restrict__ in, float* __restrict__ out,
                          const int* __restrict__ src, const int* __restrict__ dst) {
    long long t = (long long)blockIdx.x * blockDim.x + threadIdx.x;
    int e = (int)(t >> 5);
    if (e >= NE) return;
    int p = (int)(t & 31);
    int s = src[e];
    int d = dst[e];
    float4 v = ((const float4*)(in + (long long)s * DIM))[p];
    float* o = out + (long long)d * DIM + p * 4;
    atomicAdd(o + 0, v.x);
    atomicAdd(o + 1, v.y);
    atomicAdd(o + 2, v.z);
    atomicAdd(o + 3, v.w);
}

// ---------- GEMM1 (h @ W1 + b1) + per-column sum/sumsq for BN ----------
// block = 256 threads; each thread: 4 columns (c0..c0+3) x 8 row-groups.
// W1 staged in LDS (64KB). Per-block LDS reduction -> 1 atomic per column.
__global__ __launch_bounds__(256) void k_gemm1(
    const float* __restrict__ h, const float* __restrict__ W1,
    const float* __restrict__ b1, float* __restrict__ out,
    float* __restrict__ ssum, float* __restrict__ ssq) {
    __shared__ float w[DIM * DIM];
    __shared__ float redS[8 * DIM];
    __shared__ float redQ[8 * DIM];
    for (int i = threadIdx.x * 4; i < DIM * DIM; i += 1024)
        *(float4*)&w[i] = *(const float4*)&W1[i];
    __syncthreads();

    int c0 = (threadIdx.x & 31) * 4;
    int rg = threadIdx.x >> 5;  // 0..7
    float4 bias = *(const float4*)&b1[c0];
    float4 lsum = {0.f, 0.f, 0.f, 0.f};
    float4 lsq  = {0.f, 0.f, 0.f, 0.f};

    for (int pass = 0; pass < 8; ++pass) {
        int r = blockIdx.x * 64 + pass * 8 + rg;
        if (r >= NN) break;
        const float* hr = h + (long long)r * DIM;
        float4 acc = bias;
        #pragma unroll
        for (int k4 = 0; k4 < DIM / 4; ++k4) {
            float4 hv = *(const float4*)&hr[k4 * 4];
            float4 w0 = *(const float4*)&w[(k4 * 4 + 0) * DIM + c0];
            float4 w1 = *(const float4*)&w[(k4 * 4 + 1) * DIM + c0];
            float4 w2 = *(const float4*)&w[(k4 * 4 + 2) * DIM + c0];
            float4 w3 = *(const float4*)&w[(k4 * 4 + 3) * DIM + c0];
            acc.x = fmaf(hv.x, w0.x, acc.x); acc.y = fmaf(hv.x, w0.y, acc.y);
            acc.z = fmaf(hv.x, w0.z, acc.z); acc.w = fmaf(hv.x, w0.w, acc.w);
            acc.x = fmaf(hv.y, w1.x, acc.x); acc.y = fmaf(hv.y, w1.y, acc.y);
            acc.z = fmaf(hv.y, w1.z, acc.z); acc.w = fmaf(hv.y, w1.w, acc.w);
            acc.x = fmaf(hv.z, w2.x, acc.x); acc.y = fmaf(hv.z, w2.y, acc.y);
            acc.z = fmaf(hv.z, w2.z, acc.z); acc.w = fmaf(hv.z, w2.w, acc.w);
            acc.x = fmaf(hv.w, w3.x, acc.x); acc.y = fmaf(hv.w, w3.y, acc.y);
            acc.z = fmaf(hv.w, w3.z, acc.z); acc.w = fmaf(hv.w, w3.w, acc.w);
        }
        *(float4*)&out[(long long)r * DIM + c0] = acc;
        lsum.x += acc.x; lsum.y += acc.y; lsum.z += acc.z; lsum.w += acc.w;
        lsq.x += acc.x * acc.x; lsq.y += acc.y * acc.y;
        lsq.z += acc.z * acc.z; lsq.w += acc.w * acc.w;
    }

    *(float4*)&redS[rg * DIM + c0] = lsum;
    *(float4*)&redQ[rg * DIM + c0] = lsq;
    __syncthreads();
    if (threadIdx.x < DIM) {
        float s = 0.f, q = 0.f;
        #pragma unroll
        for (int g = 0; g < 8; ++g) {
            s += redS[g * DIM + threadIdx.x];
            q += redQ[g * DIM + threadIdx.x];
        }
        atomicAdd(&ssum[threadIdx.x], s);
        atomicAdd(&ssq[threadIdx.x], q);
    }
}

// ---------- BN stats finalize: scale/shift per column ----------
__global__ void k_bnstats(const float* __restrict__ ssum, const float* __restrict__ ssq,
                          const float* __restrict__ gamma, const float* __restrict__ beta,
                          float* __restrict__ scale, float* __restrict__ shift) {
    int c = threadIdx.x;
    float mu = ssum[c] / (float)NN;
    float var = ssq[c] / (float)NN - mu * mu;
    float rs = rsqrtf(var + BN_EPS);
    float sc = rs * gamma[c];
    scale[c] = sc;
    shift[c] = beta[c] - mu * sc;
}

// ---------- BN apply + SELU (in place) ----------
__global__ void k_bnselu(float* __restrict__ h, const float* __restrict__ scale,
                         const float* __restrict__ shift) {
    int i = blockIdx.x * blockDim.x + threadIdx.x;
    if (i >= NN * DIM / 4) return;
    int c0 = (i * 4) & (DIM - 1);
    float4 v = ((float4*)h)[i];
    float4 sc = *(const float4*)&scale[c0];
    float4 sh = *(const float4*)&shift[c0];
    v.x = fmaf(v.x, sc.x, sh.x);
    v.y = fmaf(v.y, sc.y, sh.y);
    v.z = fmaf(v.z, sc.z, sh.z);
    v.w = fmaf(v.w, sc.w, sh.w);
    v.x = v.x > 0.f ? SELU_SCALE * v.x : SELU_SCALE * SELU_ALPHA * (__expf(v.x) - 1.f);
    v.y = v.y > 0.f ? SELU_SCALE * v.y : SELU_SCALE * SELU_ALPHA * (__expf(v.y) - 1.f);
    v.z = v.z > 0.f ? SELU_SCALE * v.z : SELU_SCALE * SELU_ALPHA * (__expf(v.z) - 1.f);
    v.w = v.w > 0.f ? SELU_SCALE * v.w : SELU_SCALE * SELU_ALPHA * (__expf(v.w) - 1.f);
    ((float4*)h)[i] = v;
}

// ---------- head: h @ W2 + b2, softmax over 32 classes ----------
// 32 lanes per row, one class per lane; W2 (16KB) in LDS.
__global__ __launch_bounds__(256) void k_head(
    const float* __restrict__ h, const float* __restrict__ W2,
    const float* __restrict__ b2, float* __restrict__ out) {
    __shared__ float w[DIM * NC];
    __shared__ float bb[NC];
    for (int i = threadIdx.x * 4; i < DIM * NC; i += 1024)
        *(float4*)&w[i] = *(const float4*)&W2[i];
    if (threadIdx.x < NC) bb[threadIdx.x] = b2[threadIdx.x];
    __syncthreads();

    int c = threadIdx.x & 31;
    long long r = (long long)blockIdx.x * 8 + (threadIdx.x >> 5);
    if (r >= NN) return;
    const float* hr = h + r * DIM;
    float acc = bb[c];
    #pragma unroll 4
    for (int k = 0; k < DIM; ++k) acc = fmaf(hr[k], w[k * NC + c], acc);

    float m = acc;
    #pragma unroll
    for (int off = 16; off; off >>= 1) m = fmaxf(m, __shfl_xor(m, off, 32));
    float e = __expf(acc - m);
    float ssum = e;
    #pragma unroll
    for (int off = 16; off; off >>= 1) ssum += __shfl_xor(ssum, off, 32);
    out[r * NC + c] = e / ssum;
}

extern "C" void kernel_launch(void* const* d_in, const int* in_sizes, int n_in,
                              void* d_out, int out_size, void* d_ws, size_t ws_size,
                              hipStream_t stream) {
    const float* x     = (const float*)d_in[0];
    const void*  eraw  = d_in[1];
    const float* W1    = (const float*)d_in[2];
    const float* b1    = (const float*)d_in[3];
    const float* gamma = (const float*)d_in[4];
    const float* beta  = (const float*)d_in[5];
    const float* W2    = (const float*)d_in[6];
    const float* b2    = (const float*)d_in[7];
    float* out = (float*)d_out;

    // workspace layout
    float* hA   = (float*)d_ws;                    // NN*DIM
    float* hB   = hA + (size_t)NN * DIM;           // NN*DIM
    int*   es   = (int*)(hB + (size_t)NN * DIM);   // 2*NE ints
    float* ssum = (float*)(es + 2 * (size_t)NE);   // DIM
    float* ssq  = ssum + DIM;                      // DIM
    float* scale = ssq + DIM;                      // DIM
    float* shift = scale + DIM;                    // DIM
    int*   flag  = (int*)(shift + DIM);
    int* src = es;
    int* dst = es + NE;

    const int n4 = NN * DIM / 4;
    const int scatter_blocks = (int)(((long long)NE * 32 + 255) / 256);

    k_detect<<<1, 64, 0, stream>>>((const int*)eraw, flag);
    k_convert<<<(2 * NE + 255) / 256, 256, 0, stream>>>(eraw, flag, es);
    k_zero<<<1, 256, 0, stream>>>(ssum, 2 * DIM);

    // agg1: hA = x + scatter(x)
    k_copy<<<(n4 + 255) / 256, 256, 0, stream>>>((const float4*)x, (float4*)hA, n4);
    k_scatter<<<scatter_blocks, 256, 0, stream>>>(x, hA, src, dst);
    // agg2: hB = hA + scatter(hA)
    k_copy<<<(n4 + 255) / 256, 256, 0, stream>>>((const float4*)hA, (float4*)hB, n4);
    k_scatter<<<scatter_blocks, 256, 0, stream>>>(hA, hB, src, dst);
    // gemm1 + BN stats: hA = hB @ W1 + b1
    k_gemm1<<<(NN + 63) / 64, 256, 0, stream>>>(hB, W1, b1, hA, ssum, ssq);
    k_bnstats<<<1, DIM, 0, stream>>>(ssum, ssq, gamma, beta, scale, shift);
    k_bnselu<<<(n4 + 255) / 256, 256, 0, stream>>>(hA, scale, shift);
    // agg3: hB = hA + scatter(hA)
    k_copy<<<(n4 + 255) / 256, 256, 0, stream>>>((const float4*)hA, (float4*)hB, n4);
    k_scatter<<<scatter_blocks, 256, 0, stream>>>(hA, hB, src, dst);
    // head: out = softmax(hB @ W2 + b2)
    k_head<<<(NN + 7) / 8, 256, 0, stream>>>(hB, W2, b2, out);
}

// Round 2
// 508.819 us; speedup vs baseline: 8.1730x; 8.1730x over previous
//
#include <hip/hip_runtime.h>

#define NN 50000
#define NE 800000
#define DIM 128
#define NC 32
#define BN_EPS 1e-5f
#define SELU_ALPHA 1.6732632423543772f
#define SELU_SCALE 1.0507009873554805f

// ---------- edge dtype detection + conversion ----------
// If edge_index arrived as int64 (little-endian, values < 50000), every odd
// int32 word is 0. For int32 data, P(first 64 odd words all zero) ~ (1/5e4)^64.
__global__ void k_detect(const int* __restrict__ raw, int* __restrict__ flag) {
    int v = raw[2 * threadIdx.x + 1];
    unsigned long long b = __ballot(v == 0);
    if (threadIdx.x == 0) *flag = (b == 0xFFFFFFFFFFFFFFFFULL) ? 1 : 0;
}

__global__ void k_convert(const void* __restrict__ raw, const int* __restrict__ flag,
                          int* __restrict__ es) {
    int f = *flag;
    int i = blockIdx.x * blockDim.x + threadIdx.x;
    if (i < 2 * NE) {
        es[i] = f ? (int)((const long long*)raw)[i] : ((const int*)raw)[i];
    }
}

__global__ void k_zero_f(float* __restrict__ p, int n) {
    int i = blockIdx.x * blockDim.x + threadIdx.x;
    if (i < n) p[i] = 0.f;
}

__global__ void k_zero_i(int* __restrict__ p, int n) {
    int i = blockIdx.x * blockDim.x + threadIdx.x;
    if (i < n) p[i] = 0;
}

// ---------- CSR build (by destination) ----------
__global__ void k_hist(const int* __restrict__ dst, int* __restrict__ deg) {
    int e = blockIdx.x * blockDim.x + threadIdx.x;
    if (e < NE) atomicAdd(&deg[dst[e]], 1);
}

// single-block exclusive scan of deg[0..NN) -> rowptr, cursor
#define SCAN_T 1024
#define SCAN_C 49  // ceil(50000/1024)
__global__ __launch_bounds__(SCAN_T) void k_scan(const int* __restrict__ deg,
                                                 int* __restrict__ rowptr,
                                                 int* __restrict__ cursor) {
    __shared__ int part[SCAN_T];
    int t = threadIdx.x;
    int c0 = t * SCAN_C;
    int s = 0;
    for (int i = 0; i < SCAN_C; ++i) {
        int idx = c0 + i;
        if (idx < NN) s += deg[idx];
    }
    part[t] = s;
    __syncthreads();
    for (int off = 1; off < SCAN_T; off <<= 1) {
        int v = (t >= off) ? part[t - off] : 0;
        __syncthreads();
        part[t] += v;
        __syncthreads();
    }
    if (t == SCAN_T - 1) rowptr[NN] = part[SCAN_T - 1];
    int run = (t == 0) ? 0 : part[t - 1];
    for (int i = 0; i < SCAN_C; ++i) {
        int idx = c0 + i;
        if (idx < NN) {
            rowptr[idx] = run;
            cursor[idx] = run;
            run += deg[idx];
        }
    }
}

__global__ void k_fill(const int* __restrict__ src, const int* __restrict__ dst,
                       int* __restrict__ cursor, int* __restrict__ eidx) {
    int e = blockIdx.x * blockDim.x + threadIdx.x;
    if (e < NE) {
        int p = atomicAdd(&cursor[dst[e]], 1);
        eidx[p] = src[e];
    }
}

// ---------- aggregation: out[i] = in[i] + sum_{j in neigh(i)} in[j] ----------
// one wave (64 lanes) per node; lane owns a float2 of the 128-wide row.
__global__ __launch_bounds__(256) void k_gather(const float* __restrict__ in,
                                                float* __restrict__ out,
                                                const int* __restrict__ rowptr,
                                                const int* __restrict__ eidx) {
    int node = blockIdx.x * 4 + (threadIdx.x >> 6);
    if (node >= NN) return;
    int lane = threadIdx.x & 63;
    const float2* base = (const float2*)in;
    float2 acc = base[(size_t)node * 64 + lane];  // self-loop
    int b = rowptr[node], e = rowptr[node + 1];
    int j = b;
    for (; j + 1 < e; j += 2) {
        int s0 = eidx[j];
        int s1 = eidx[j + 1];
        float2 v0 = base[(size_t)s0 * 64 + lane];
        float2 v1 = base[(size_t)s1 * 64 + lane];
        acc.x += v0.x; acc.y += v0.y;
        acc.x += v1.x; acc.y += v1.y;
    }
    if (j < e) {
        int s0 = eidx[j];
        float2 v0 = base[(size_t)s0 * 64 + lane];
        acc.x += v0.x; acc.y += v0.y;
    }
    ((float2*)out)[(size_t)node * 64 + lane] = acc;
}

// ---------- GEMM1 (h @ W1 + b1) + per-column sum/sumsq for BN ----------
__global__ __launch_bounds__(256) void k_gemm1(
    const float* __restrict__ h, const float* __restrict__ W1,
    const float* __restrict__ b1, float* __restrict__ out,
    float* __restrict__ ssum, float* __restrict__ ssq) {
    __shared__ float w[DIM * DIM];
    __shared__ float redS[8 * DIM];
    __shared__ float redQ[8 * DIM];
    for (int i = threadIdx.x * 4; i < DIM * DIM; i += 1024)
        *(float4*)&w[i] = *(const float4*)&W1[i];
    __syncthreads();

    int c0 = (threadIdx.x & 31) * 4;
    int rg = threadIdx.x >> 5;  // 0..7
    float4 bias = *(const float4*)&b1[c0];
    float4 lsum = {0.f, 0.f, 0.f, 0.f};
    float4 lsq  = {0.f, 0.f, 0.f, 0.f};

    for (int pass = 0; pass < 8; ++pass) {
        int r = blockIdx.x * 64 + pass * 8 + rg;
        if (r >= NN) break;
        const float* hr = h + (long long)r * DIM;
        float4 acc = bias;
        #pragma unroll
        for (int k4 = 0; k4 < DIM / 4; ++k4) {
            float4 hv = *(const float4*)&hr[k4 * 4];
            float4 w0 = *(const float4*)&w[(k4 * 4 + 0) * DIM + c0];
            float4 w1 = *(const float4*)&w[(k4 * 4 + 1) * DIM + c0];
            float4 w2 = *(const float4*)&w[(k4 * 4 + 2) * DIM + c0];
            float4 w3 = *(const float4*)&w[(k4 * 4 + 3) * DIM + c0];
            acc.x = fmaf(hv.x, w0.x, acc.x); acc.y = fmaf(hv.x, w0.y, acc.y);
            acc.z = fmaf(hv.x, w0.z, acc.z); acc.w = fmaf(hv.x, w0.w, acc.w);
            acc.x = fmaf(hv.y, w1.x, acc.x); acc.y = fmaf(hv.y, w1.y, acc.y);
            acc.z = fmaf(hv.y, w1.z, acc.z); acc.w = fmaf(hv.y, w1.w, acc.w);
            acc.x = fmaf(hv.z, w2.x, acc.x); acc.y = fmaf(hv.z, w2.y, acc.y);
            acc.z = fmaf(hv.z, w2.z, acc.z); acc.w = fmaf(hv.z, w2.w, acc.w);
            acc.x = fmaf(hv.w, w3.x, acc.x); acc.y = fmaf(hv.w, w3.y, acc.y);
            acc.z = fmaf(hv.w, w3.z, acc.z); acc.w = fmaf(hv.w, w3.w, acc.w);
        }
        *(float4*)&out[(long long)r * DIM + c0] = acc;
        lsum.x += acc.x; lsum.y += acc.y; lsum.z += acc.z; lsum.w += acc.w;
        lsq.x += acc.x * acc.x; lsq.y += acc.y * acc.y;
        lsq.z += acc.z * acc.z; lsq.w += acc.w * acc.w;
    }

    *(float4*)&redS[rg * DIM + c0] = lsum;
    *(float4*)&redQ[rg * DIM + c0] = lsq;
    __syncthreads();
    if (threadIdx.x < DIM) {
        float s = 0.f, q = 0.f;
        #pragma unroll
        for (int g = 0; g < 8; ++g) {
            s += redS[g * DIM + threadIdx.x];
            q += redQ[g * DIM + threadIdx.x];
        }
        atomicAdd(&ssum[threadIdx.x], s);
        atomicAdd(&ssq[threadIdx.x], q);
    }
}

// ---------- BN stats finalize ----------
__global__ void k_bnstats(const float* __restrict__ ssum, const float* __restrict__ ssq,
                          const float* __restrict__ gamma, const float* __restrict__ beta,
                          float* __restrict__ scale, float* __restrict__ shift) {
    int c = threadIdx.x;
    float mu = ssum[c] / (float)NN;
    float var = ssq[c] / (float)NN - mu * mu;
    float rs = rsqrtf(var + BN_EPS);
    float sc = rs * gamma[c];
    scale[c] = sc;
    shift[c] = beta[c] - mu * sc;
}

// ---------- BN apply + SELU (in place) ----------
__global__ void k_bnselu(float* __restrict__ h, const float* __restrict__ scale,
                         const float* __restrict__ shift) {
    int i = blockIdx.x * blockDim.x + threadIdx.x;
    if (i >= NN * DIM / 4) return;
    int c0 = (i * 4) & (DIM - 1);
    float4 v = ((float4*)h)[i];
    float4 sc = *(const float4*)&scale[c0];
    float4 sh = *(const float4*)&shift[c0];
    v.x = fmaf(v.x, sc.x, sh.x);
    v.y = fmaf(v.y, sc.y, sh.y);
    v.z = fmaf(v.z, sc.z, sh.z);
    v.w = fmaf(v.w, sc.w, sh.w);
    v.x = v.x > 0.f ? SELU_SCALE * v.x : SELU_SCALE * SELU_ALPHA * (__expf(v.x) - 1.f);
    v.y = v.y > 0.f ? SELU_SCALE * v.y : SELU_SCALE * SELU_ALPHA * (__expf(v.y) - 1.f);
    v.z = v.z > 0.f ? SELU_SCALE * v.z : SELU_SCALE * SELU_ALPHA * (__expf(v.z) - 1.f);
    v.w = v.w > 0.f ? SELU_SCALE * v.w : SELU_SCALE * SELU_ALPHA * (__expf(v.w) - 1.f);
    ((float4*)h)[i] = v;
}

// ---------- head: h @ W2 + b2, softmax over 32 classes ----------
__global__ __launch_bounds__(256) void k_head(
    const float* __restrict__ h, const float* __restrict__ W2,
    const float* __restrict__ b2, float* __restrict__ out) {
    __shared__ float w[DIM * NC];
    __shared__ float bb[NC];
    for (int i = threadIdx.x * 4; i < DIM * NC; i += 1024)
        *(float4*)&w[i] = *(const float4*)&W2[i];
    if (threadIdx.x < NC) bb[threadIdx.x] = b2[threadIdx.x];
    __syncthreads();

    int c = threadIdx.x & 31;
    long long r = (long long)blockIdx.x * 8 + (threadIdx.x >> 5);
    if (r >= NN) return;
    const float* hr = h + r * DIM;
    float acc = bb[c];
    #pragma unroll 4
    for (int k = 0; k < DIM; ++k) acc = fmaf(hr[k], w[k * NC + c], acc);

    float m = acc;
    #pragma unroll
    for (int off = 16; off; off >>= 1) m = fmaxf(m, __shfl_xor(m, off, 32));
    float e = __expf(acc - m);
    float ssum = e;
    #pragma unroll
    for (int off = 16; off; off >>= 1) ssum += __shfl_xor(ssum, off, 32);
    out[r * NC + c] = e / ssum;
}

extern "C" void kernel_launch(void* const* d_in, const int* in_sizes, int n_in,
                              void* d_out, int out_size, void* d_ws, size_t ws_size,
                              hipStream_t stream) {
    const float* x     = (const float*)d_in[0];
    const void*  eraw  = d_in[1];
    const float* W1    = (const float*)d_in[2];
    const float* b1    = (const float*)d_in[3];
    const float* gamma = (const float*)d_in[4];
    const float* beta  = (const float*)d_in[5];
    const float* W2    = (const float*)d_in[6];
    const float* b2    = (const float*)d_in[7];
    float* out = (float*)d_out;

    // workspace layout
    float* hA    = (float*)d_ws;                     // NN*DIM
    float* hB    = hA + (size_t)NN * DIM;            // NN*DIM
    int*   es    = (int*)(hB + (size_t)NN * DIM);    // 2*NE
    int*   eidx  = es + 2 * (size_t)NE;              // NE
    int*   deg   = eidx + NE;                        // NN
    int*   rowptr= deg + NN;                         // NN+1
    int*   cursor= rowptr + NN + 1;                  // NN
    float* ssum  = (float*)(cursor + NN);            // DIM
    float* ssq   = ssum + DIM;                       // DIM
    float* scale = ssq + DIM;                        // DIM
    float* shift = scale + DIM;                      // DIM
    int*   flag  = (int*)(shift + DIM);
    int* src = es;
    int* dst = es + NE;

    const int n4 = NN * DIM / 4;

    // edge canonicalization + CSR build
    k_detect<<<1, 64, 0, stream>>>((const int*)eraw, flag);
    k_convert<<<(2 * NE + 255) / 256, 256, 0, stream>>>(eraw, flag, es);
    k_zero_i<<<(NN + 255) / 256, 256, 0, stream>>>(deg, NN);
    k_zero_f<<<1, 256, 0, stream>>>(ssum, 2 * DIM);
    k_hist<<<(NE + 255) / 256, 256, 0, stream>>>(dst, deg);
    k_scan<<<1, SCAN_T, 0, stream>>>(deg, rowptr, cursor);
    k_fill<<<(NE + 255) / 256, 256, 0, stream>>>(src, dst, cursor, eidx);

    const int gather_blocks = (NN + 3) / 4;
    // agg1: hA = x + gather(x)
    k_gather<<<gather_blocks, 256, 0, stream>>>(x, hA, rowptr, eidx);
    // agg2: hB = hA + gather(hA)
    k_gather<<<gather_blocks, 256, 0, stream>>>(hA, hB, rowptr, eidx);
    // gemm1 + BN stats: hA = hB @ W1 + b1
    k_gemm1<<<(NN + 63) / 64, 256, 0, stream>>>(hB, W1, b1, hA, ssum, ssq);
    k_bnstats<<<1, DIM, 0, stream>>>(ssum, ssq, gamma, beta, scale, shift);
    k_bnselu<<<(n4 + 255) / 256, 256, 0, stream>>>(hA, scale, shift);
    // agg3: hB = hA + gather(hA)
    k_gather<<<gather_blocks, 256, 0, stream>>>(hA, hB, rowptr, eidx);
    // head: out = softmax(hB @ W2 + b2)
    k_head<<<(NN + 7) / 8, 256, 0, stream>>>(hB, W2, b2, out);
}

// Round 3
// 394.803 us; speedup vs baseline: 10.5332x; 1.2888x over previous
//
#include <hip/hip_runtime.h>

#define NN 50000
#define NE 800000
#define DIM 128
#define NC 32
#define N4 12500          // NN/4 int4 chunks of deg
#define NSB 49            // ceil(N4 / 256) scan blocks
#define BN_EPS 1e-5f
#define SELU_ALPHA 1.6732632423543772f
#define SELU_SCALE 1.0507009873554805f

// ---------- edge dtype detection + conversion ----------
__global__ void k_detect(const int* __restrict__ raw, int* __restrict__ flag) {
    int v = raw[2 * threadIdx.x + 1];
    unsigned long long b = __ballot(v == 0);
    if (threadIdx.x == 0) *flag = (b == 0xFFFFFFFFFFFFFFFFULL) ? 1 : 0;
}

__global__ void k_convert(const void* __restrict__ raw, const int* __restrict__ flag,
                          int* __restrict__ es) {
    int f = *flag;
    int i = blockIdx.x * blockDim.x + threadIdx.x;
    if (i < 2 * NE) {
        es[i] = f ? (int)((const long long*)raw)[i] : ((const int*)raw)[i];
    }
}

__global__ void k_zero_f(float* __restrict__ p, int n) {
    int i = blockIdx.x * blockDim.x + threadIdx.x;
    if (i < n) p[i] = 0.f;
}

__global__ void k_zero_i(int* __restrict__ p, int n) {
    int i = blockIdx.x * blockDim.x + threadIdx.x;
    if (i < n) p[i] = 0;
}

// ---------- CSR build (by destination) ----------
__global__ void k_hist(const int* __restrict__ dst, int* __restrict__ deg) {
    int e = blockIdx.x * blockDim.x + threadIdx.x;
    if (e < NE) atomicAdd(&deg[dst[e]], 1);
}

// decoupled 3-phase exclusive scan of deg -> rowptr, cursor
__global__ __launch_bounds__(256) void k_bsum(const int* __restrict__ deg,
                                              int* __restrict__ bsum) {
    int g = blockIdx.x * 256 + threadIdx.x;
    int4 v = {0, 0, 0, 0};
    if (g < N4) v = ((const int4*)deg)[g];
    int s = v.x + v.y + v.z + v.w;
    #pragma unroll
    for (int off = 1; off < 64; off <<= 1) s += __shfl_xor(s, off, 64);
    __shared__ int ws[4];
    if ((threadIdx.x & 63) == 0) ws[threadIdx.x >> 6] = s;
    __syncthreads();
    if (threadIdx.x == 0) bsum[blockIdx.x] = ws[0] + ws[1] + ws[2] + ws[3];
}

__global__ void k_bscan(const int* __restrict__ bsum, int* __restrict__ boff,
                        int* __restrict__ rowptr) {
    int lane = threadIdx.x;  // 64 threads
    int v = (lane < NSB) ? bsum[lane] : 0;
    int inc = v;
    #pragma unroll
    for (int off = 1; off < 64; off <<= 1) {
        int u = __shfl_up(inc, off, 64);
        if (lane >= off) inc += u;
    }
    if (lane < NSB) boff[lane] = inc - v;
    if (lane == 63) rowptr[NN] = inc;  // grand total
}

__global__ __launch_bounds__(256) void k_scanfill(const int* __restrict__ deg,
                                                  const int* __restrict__ boff,
                                                  int* __restrict__ rowptr,
                                                  int* __restrict__ cursor) {
    int g = blockIdx.x * 256 + threadIdx.x;
    int4 v = {0, 0, 0, 0};
    if (g < N4) v = ((const int4*)deg)[g];
    int s = v.x + v.y + v.z + v.w;
    int inc = s;
    int lane = threadIdx.x & 63;
    #pragma unroll
    for (int off = 1; off < 64; off <<= 1) {
        int u = __shfl_up(inc, off, 64);
        if (lane >= off) inc += u;
    }
    __shared__ int wtot[4];
    if (lane == 63) wtot[threadIdx.x >> 6] = inc;
    __syncthreads();
    int wid = threadIdx.x >> 6;
    int pre = 0;
    for (int w = 0; w < wid; ++w) pre += wtot[w];
    int base = boff[blockIdx.x] + pre + (inc - s);
    if (g < N4) {
        int4 r;
        r.x = base;
        r.y = r.x + v.x;
        r.z = r.y + v.y;
        r.w = r.z + v.z;
        ((int4*)rowptr)[g] = r;
        ((int4*)cursor)[g] = r;
    }
}

__global__ void k_fill(const int* __restrict__ src, const int* __restrict__ dst,
                       int* __restrict__ cursor, int* __restrict__ eidx) {
    int e = blockIdx.x * blockDim.x + threadIdx.x;
    if (e < NE) {
        int p = atomicAdd(&cursor[dst[e]], 1);
        eidx[p] = src[e];
    }
}

// ---------- aggregation: out[i] = in[i] + sum_{j in neigh(i)} in[j] ----------
__global__ __launch_bounds__(256) void k_gather(const float* __restrict__ in,
                                                float* __restrict__ out,
                                                const int* __restrict__ rowptr,
                                                const int* __restrict__ eidx) {
    int node = blockIdx.x * 4 + (threadIdx.x >> 6);
    if (node >= NN) return;
    int lane = threadIdx.x & 63;
    const float2* base = (const float2*)in;
    float2 acc = base[(size_t)node * 64 + lane];  // self-loop
    int b = rowptr[node], e = rowptr[node + 1];
    int j = b;
    for (; j + 1 < e; j += 2) {
        int s0 = eidx[j];
        int s1 = eidx[j + 1];
        float2 v0 = base[(size_t)s0 * 64 + lane];
        float2 v1 = base[(size_t)s1 * 64 + lane];
        acc.x += v0.x; acc.y += v0.y;
        acc.x += v1.x; acc.y += v1.y;
    }
    if (j < e) {
        int s0 = eidx[j];
        float2 v0 = base[(size_t)s0 * 64 + lane];
        acc.x += v0.x; acc.y += v0.y;
    }
    ((float2*)out)[(size_t)node * 64 + lane] = acc;
}

// ---------- GEMM1 (h @ W1 + b1) + per-column sum/sumsq for BN ----------
__global__ __launch_bounds__(256) void k_gemm1(
    const float* __restrict__ h, const float* __restrict__ W1,
    const float* __restrict__ b1, float* __restrict__ out,
    float* __restrict__ ssum, float* __restrict__ ssq) {
    __shared__ float w[DIM * DIM];
    __shared__ float redS[8 * DIM];
    __shared__ float redQ[8 * DIM];
    for (int i = threadIdx.x * 4; i < DIM * DIM; i += 1024)
        *(float4*)&w[i] = *(const float4*)&W1[i];
    __syncthreads();

    int c0 = (threadIdx.x & 31) * 4;
    int rg = threadIdx.x >> 5;  // 0..7
    float4 bias = *(const float4*)&b1[c0];
    float4 lsum = {0.f, 0.f, 0.f, 0.f};
    float4 lsq  = {0.f, 0.f, 0.f, 0.f};

    for (int pass = 0; pass < 8; ++pass) {
        int r = blockIdx.x * 64 + pass * 8 + rg;
        if (r >= NN) break;
        const float* hr = h + (long long)r * DIM;
        float4 acc = bias;
        #pragma unroll
        for (int k4 = 0; k4 < DIM / 4; ++k4) {
            float4 hv = *(const float4*)&hr[k4 * 4];
            float4 w0 = *(const float4*)&w[(k4 * 4 + 0) * DIM + c0];
            float4 w1 = *(const float4*)&w[(k4 * 4 + 1) * DIM + c0];
            float4 w2 = *(const float4*)&w[(k4 * 4 + 2) * DIM + c0];
            float4 w3 = *(const float4*)&w[(k4 * 4 + 3) * DIM + c0];
            acc.x = fmaf(hv.x, w0.x, acc.x); acc.y = fmaf(hv.x, w0.y, acc.y);
            acc.z = fmaf(hv.x, w0.z, acc.z); acc.w = fmaf(hv.x, w0.w, acc.w);
            acc.x = fmaf(hv.y, w1.x, acc.x); acc.y = fmaf(hv.y, w1.y, acc.y);
            acc.z = fmaf(hv.y, w1.z, acc.z); acc.w = fmaf(hv.y, w1.w, acc.w);
            acc.x = fmaf(hv.z, w2.x, acc.x); acc.y = fmaf(hv.z, w2.y, acc.y);
            acc.z = fmaf(hv.z, w2.z, acc.z); acc.w = fmaf(hv.z, w2.w, acc.w);
            acc.x = fmaf(hv.w, w3.x, acc.x); acc.y = fmaf(hv.w, w3.y, acc.y);
            acc.z = fmaf(hv.w, w3.z, acc.z); acc.w = fmaf(hv.w, w3.w, acc.w);
        }
        *(float4*)&out[(long long)r * DIM + c0] = acc;
        lsum.x += acc.x; lsum.y += acc.y; lsum.z += acc.z; lsum.w += acc.w;
        lsq.x += acc.x * acc.x; lsq.y += acc.y * acc.y;
        lsq.z += acc.z * acc.z; lsq.w += acc.w * acc.w;
    }

    *(float4*)&redS[rg * DIM + c0] = lsum;
    *(float4*)&redQ[rg * DIM + c0] = lsq;
    __syncthreads();
    if (threadIdx.x < DIM) {
        float s = 0.f, q = 0.f;
        #pragma unroll
        for (int g = 0; g < 8; ++g) {
            s += redS[g * DIM + threadIdx.x];
            q += redQ[g * DIM + threadIdx.x];
        }
        atomicAdd(&ssum[threadIdx.x], s);
        atomicAdd(&ssq[threadIdx.x], q);
    }
}

// ---------- BN stats finalize ----------
__global__ void k_bnstats(const float* __restrict__ ssum, const float* __restrict__ ssq,
                          const float* __restrict__ gamma, const float* __restrict__ beta,
                          float* __restrict__ scale, float* __restrict__ shift) {
    int c = threadIdx.x;
    float mu = ssum[c] / (float)NN;
    float var = ssq[c] / (float)NN - mu * mu;
    float rs = rsqrtf(var + BN_EPS);
    float sc = rs * gamma[c];
    scale[c] = sc;
    shift[c] = beta[c] - mu * sc;
}

// ---------- BN apply + SELU (in place) ----------
__global__ void k_bnselu(float* __restrict__ h, const float* __restrict__ scale,
                         const float* __restrict__ shift) {
    int i = blockIdx.x * blockDim.x + threadIdx.x;
    if (i >= NN * DIM / 4) return;
    int c0 = (i * 4) & (DIM - 1);
    float4 v = ((float4*)h)[i];
    float4 sc = *(const float4*)&scale[c0];
    float4 sh = *(const float4*)&shift[c0];
    v.x = fmaf(v.x, sc.x, sh.x);
    v.y = fmaf(v.y, sc.y, sh.y);
    v.z = fmaf(v.z, sc.z, sh.z);
    v.w = fmaf(v.w, sc.w, sh.w);
    v.x = v.x > 0.f ? SELU_SCALE * v.x : SELU_SCALE * SELU_ALPHA * (__expf(v.x) - 1.f);
    v.y = v.y > 0.f ? SELU_SCALE * v.y : SELU_SCALE * SELU_ALPHA * (__expf(v.y) - 1.f);
    v.z = v.z > 0.f ? SELU_SCALE * v.z : SELU_SCALE * SELU_ALPHA * (__expf(v.z) - 1.f);
    v.w = v.w > 0.f ? SELU_SCALE * v.w : SELU_SCALE * SELU_ALPHA * (__expf(v.w) - 1.f);
    ((float4*)h)[i] = v;
}

// ---------- head: h @ W2 + b2, softmax over 32 classes ----------
__global__ __launch_bounds__(256) void k_head(
    const float* __restrict__ h, const float* __restrict__ W2,
    const float* __restrict__ b2, float* __restrict__ out) {
    __shared__ float w[DIM * NC];
    __shared__ float bb[NC];
    for (int i = threadIdx.x * 4; i < DIM * NC; i += 1024)
        *(float4*)&w[i] = *(const float4*)&W2[i];
    if (threadIdx.x < NC) bb[threadIdx.x] = b2[threadIdx.x];
    __syncthreads();

    int c = threadIdx.x & 31;
    long long r = (long long)blockIdx.x * 8 + (threadIdx.x >> 5);
    if (r >= NN) return;
    const float* hr = h + r * DIM;
    float acc = bb[c];
    #pragma unroll 4
    for (int k = 0; k < DIM; ++k) acc = fmaf(hr[k], w[k * NC + c], acc);

    float m = acc;
    #pragma unroll
    for (int off = 16; off; off >>= 1) m = fmaxf(m, __shfl_xor(m, off, 32));
    float e = __expf(acc - m);
    float ssum = e;
    #pragma unroll
    for (int off = 16; off; off >>= 1) ssum += __shfl_xor(ssum, off, 32);
    out[r * NC + c] = e / ssum;
}

extern "C" void kernel_launch(void* const* d_in, const int* in_sizes, int n_in,
                              void* d_out, int out_size, void* d_ws, size_t ws_size,
                              hipStream_t stream) {
    const float* x     = (const float*)d_in[0];
    const void*  eraw  = d_in[1];
    const float* W1    = (const float*)d_in[2];
    const float* b1    = (const float*)d_in[3];
    const float* gamma = (const float*)d_in[4];
    const float* beta  = (const float*)d_in[5];
    const float* W2    = (const float*)d_in[6];
    const float* b2    = (const float*)d_in[7];
    float* out = (float*)d_out;

    // workspace layout (all 16B-aligned)
    float* hA    = (float*)d_ws;                     // NN*DIM
    float* hB    = hA + (size_t)NN * DIM;            // NN*DIM
    int*   es    = (int*)(hB + (size_t)NN * DIM);    // 2*NE
    int*   eidx  = es + 2 * (size_t)NE;              // NE
    int*   deg   = eidx + NE;                        // NN
    int*   rowptr= deg + NN;                         // NN+4 (padded for alignment)
    int*   cursor= rowptr + NN + 4;                  // NN
    int*   bsum  = cursor + NN;                      // 64
    int*   boff  = bsum + 64;                        // 64
    float* ssum  = (float*)(boff + 64);              // DIM
    float* ssq   = ssum + DIM;                       // DIM
    float* scale = ssq + DIM;                        // DIM
    float* shift = scale + DIM;                      // DIM
    int*   flag  = (int*)(shift + DIM);
    int* src = es;
    int* dst = es + NE;

    const int n4 = NN * DIM / 4;

    // edge canonicalization + CSR build
    k_detect<<<1, 64, 0, stream>>>((const int*)eraw, flag);
    k_convert<<<(2 * NE + 255) / 256, 256, 0, stream>>>(eraw, flag, es);
    k_zero_i<<<(NN + 255) / 256, 256, 0, stream>>>(deg, NN);
    k_zero_f<<<1, 256, 0, stream>>>(ssum, 2 * DIM);
    k_hist<<<(NE + 255) / 256, 256, 0, stream>>>(dst, deg);
    k_bsum<<<NSB, 256, 0, stream>>>(deg, bsum);
    k_bscan<<<1, 64, 0, stream>>>(bsum, boff, rowptr);
    k_scanfill<<<NSB, 256, 0, stream>>>(deg, boff, rowptr, cursor);
    k_fill<<<(NE + 255) / 256, 256, 0, stream>>>(src, dst, cursor, eidx);

    const int gather_blocks = (NN + 3) / 4;
    // agg1: hA = x + gather(x)
    k_gather<<<gather_blocks, 256, 0, stream>>>(x, hA, rowptr, eidx);
    // agg2: hB = hA + gather(hA)
    k_gather<<<gather_blocks, 256, 0, stream>>>(hA, hB, rowptr, eidx);
    // gemm1 + BN stats: hA = hB @ W1 + b1
    k_gemm1<<<(NN + 63) / 64, 256, 0, stream>>>(hB, W1, b1, hA, ssum, ssq);
    k_bnstats<<<1, DIM, 0, stream>>>(ssum, ssq, gamma, beta, scale, shift);
    k_bnselu<<<(n4 + 255) / 256, 256, 0, stream>>>(hA, scale, shift);
    // agg3: hB = hA + gather(hA)
    k_gather<<<gather_blocks, 256, 0, stream>>>(hA, hB, rowptr, eidx);
    // head: out = softmax(hB @ W2 + b2)
    k_head<<<(NN + 7) / 8, 256, 0, stream>>>(hB, W2, b2, out);
}

// Round 4
// 346.879 us; speedup vs baseline: 11.9885x; 1.1382x over previous
//
#include <hip/hip_runtime.h>

#define NN 50000
#define NE 800000
#define DIM 128
#define NC 32
#define N4 12500          // NN/4 int4 chunks of deg
#define NSB 49            // ceil(N4 / 256) scan blocks
#define BN_EPS 1e-5f
#define SELU_ALPHA 1.6732632423543772f
#define SELU_SCALE 1.0507009873554805f

// acc[c] += sum_i hv[i] * wi[c]
#define FMA16(acc, hv, w0, w1, w2, w3)                                   \
    acc.x = fmaf(hv.x, w0.x, acc.x); acc.y = fmaf(hv.x, w0.y, acc.y);    \
    acc.z = fmaf(hv.x, w0.z, acc.z); acc.w = fmaf(hv.x, w0.w, acc.w);    \
    acc.x = fmaf(hv.y, w1.x, acc.x); acc.y = fmaf(hv.y, w1.y, acc.y);    \
    acc.z = fmaf(hv.y, w1.z, acc.z); acc.w = fmaf(hv.y, w1.w, acc.w);    \
    acc.x = fmaf(hv.z, w2.x, acc.x); acc.y = fmaf(hv.z, w2.y, acc.y);    \
    acc.z = fmaf(hv.z, w2.z, acc.z); acc.w = fmaf(hv.z, w2.w, acc.w);    \
    acc.x = fmaf(hv.w, w3.x, acc.x); acc.y = fmaf(hv.w, w3.y, acc.y);    \
    acc.z = fmaf(hv.w, w3.z, acc.z); acc.w = fmaf(hv.w, w3.w, acc.w);

// ---------- edge dtype detection + conversion ----------
__global__ void k_detect(const int* __restrict__ raw, int* __restrict__ flag) {
    int v = raw[2 * threadIdx.x + 1];
    unsigned long long b = __ballot(v == 0);
    if (threadIdx.x == 0) *flag = (b == 0xFFFFFFFFFFFFFFFFULL) ? 1 : 0;
}

__global__ void k_convert(const void* __restrict__ raw, const int* __restrict__ flag,
                          int* __restrict__ es) {
    int f = *flag;
    int i = blockIdx.x * blockDim.x + threadIdx.x;
    if (i < 2 * NE) {
        es[i] = f ? (int)((const long long*)raw)[i] : ((const int*)raw)[i];
    }
}

__global__ void k_zero_f(float* __restrict__ p, int n) {
    int i = blockIdx.x * blockDim.x + threadIdx.x;
    if (i < n) p[i] = 0.f;
}

__global__ void k_zero_i(int* __restrict__ p, int n) {
    int i = blockIdx.x * blockDim.x + threadIdx.x;
    if (i < n) p[i] = 0;
}

// ---------- CSR build (by destination) ----------
__global__ void k_hist(const int* __restrict__ dst, int* __restrict__ deg) {
    int e = blockIdx.x * blockDim.x + threadIdx.x;
    if (e < NE) atomicAdd(&deg[dst[e]], 1);
}

__global__ __launch_bounds__(256) void k_bsum(const int* __restrict__ deg,
                                              int* __restrict__ bsum) {
    int g = blockIdx.x * 256 + threadIdx.x;
    int4 v = {0, 0, 0, 0};
    if (g < N4) v = ((const int4*)deg)[g];
    int s = v.x + v.y + v.z + v.w;
    #pragma unroll
    for (int off = 1; off < 64; off <<= 1) s += __shfl_xor(s, off, 64);
    __shared__ int ws[4];
    if ((threadIdx.x & 63) == 0) ws[threadIdx.x >> 6] = s;
    __syncthreads();
    if (threadIdx.x == 0) bsum[blockIdx.x] = ws[0] + ws[1] + ws[2] + ws[3];
}

__global__ void k_bscan(const int* __restrict__ bsum, int* __restrict__ boff,
                        int* __restrict__ rowptr) {
    int lane = threadIdx.x;  // 64 threads
    int v = (lane < NSB) ? bsum[lane] : 0;
    int inc = v;
    #pragma unroll
    for (int off = 1; off < 64; off <<= 1) {
        int u = __shfl_up(inc, off, 64);
        if (lane >= off) inc += u;
    }
    if (lane < NSB) boff[lane] = inc - v;
    if (lane == 63) rowptr[NN] = inc;  // grand total
}

__global__ __launch_bounds__(256) void k_scanfill(const int* __restrict__ deg,
                                                  const int* __restrict__ boff,
                                                  int* __restrict__ rowptr,
                                                  int* __restrict__ cursor) {
    int g = blockIdx.x * 256 + threadIdx.x;
    int4 v = {0, 0, 0, 0};
    if (g < N4) v = ((const int4*)deg)[g];
    int s = v.x + v.y + v.z + v.w;
    int inc = s;
    int lane = threadIdx.x & 63;
    #pragma unroll
    for (int off = 1; off < 64; off <<= 1) {
        int u = __shfl_up(inc, off, 64);
        if (lane >= off) inc += u;
    }
    __shared__ int wtot[4];
    if (lane == 63) wtot[threadIdx.x >> 6] = inc;
    __syncthreads();
    int wid = threadIdx.x >> 6;
    int pre = 0;
    for (int w = 0; w < wid; ++w) pre += wtot[w];
    int base = boff[blockIdx.x] + pre + (inc - s);
    if (g < N4) {
        int4 r;
        r.x = base;
        r.y = r.x + v.x;
        r.z = r.y + v.y;
        r.w = r.z + v.z;
        ((int4*)rowptr)[g] = r;
        ((int4*)cursor)[g] = r;
    }
}

__global__ void k_fill(const int* __restrict__ src, const int* __restrict__ dst,
                       int* __restrict__ cursor, int* __restrict__ eidx) {
    int e = blockIdx.x * blockDim.x + threadIdx.x;
    if (e < NE) {
        int p = atomicAdd(&cursor[dst[e]], 1);
        eidx[p] = src[e];
    }
}

// ---------- aggregation: out[i] = in[i] + sum_{j in neigh(i)} in[j] ----------
__global__ __launch_bounds__(256) void k_gather(const float* __restrict__ in,
                                                float* __restrict__ out,
                                                const int* __restrict__ rowptr,
                                                const int* __restrict__ eidx) {
    int node = blockIdx.x * 4 + (threadIdx.x >> 6);
    if (node >= NN) return;
    int lane = threadIdx.x & 63;
    const float2* base = (const float2*)in;
    float2 acc = base[(size_t)node * 64 + lane];  // self-loop
    int b = rowptr[node], e = rowptr[node + 1];
    int j = b;
    for (; j + 1 < e; j += 2) {
        int s0 = eidx[j];
        int s1 = eidx[j + 1];
        float2 v0 = base[(size_t)s0 * 64 + lane];
        float2 v1 = base[(size_t)s1 * 64 + lane];
        acc.x += v0.x; acc.y += v0.y;
        acc.x += v1.x; acc.y += v1.y;
    }
    if (j < e) {
        int s0 = eidx[j];
        float2 v0 = base[(size_t)s0 * 64 + lane];
        acc.x += v0.x; acc.y += v0.y;
    }
    ((float2*)out)[(size_t)node * 64 + lane] = acc;
}

// ---------- GEMM1 (h @ W1 + b1) + per-column sum/sumsq for BN ----------
// 256 thr: c0=(tid&31)*4 covers 128 cols; rg=tid>>5; 4 rows/thread, 4 passes
// -> 128 rows/block. 4 LDS reads feed 64 FMAs per k4 (was 16).
__global__ __launch_bounds__(256) void k_gemm1(
    const float* __restrict__ h, const float* __restrict__ W1,
    const float* __restrict__ b1, float* __restrict__ out,
    float* __restrict__ ssum, float* __restrict__ ssq) {
    __shared__ float w[DIM * DIM];
    __shared__ float redS[8 * DIM];
    __shared__ float redQ[8 * DIM];
    for (int i = threadIdx.x * 4; i < DIM * DIM; i += 1024)
        *(float4*)&w[i] = *(const float4*)&W1[i];
    __syncthreads();

    int c0 = (threadIdx.x & 31) * 4;
    int rg = threadIdx.x >> 5;  // 0..7
    float4 bias = *(const float4*)&b1[c0];
    float4 lsum = {0.f, 0.f, 0.f, 0.f};
    float4 lsq  = {0.f, 0.f, 0.f, 0.f};

    for (int pass = 0; pass < 4; ++pass) {
        int r0 = blockIdx.x * 128 + pass * 32 + rg * 4;
        if (r0 >= NN) break;  // NN%4==0 -> 4-row groups are all-or-nothing
        const float* h0 = h + (size_t)r0 * DIM;
        float4 a0 = bias, a1 = bias, a2 = bias, a3 = bias;
        #pragma unroll 4
        for (int k4 = 0; k4 < DIM / 4; ++k4) {
            float4 hv0 = *(const float4*)&h0[k4 * 4];
            float4 hv1 = *(const float4*)&h0[DIM + k4 * 4];
            float4 hv2 = *(const float4*)&h0[2 * DIM + k4 * 4];
            float4 hv3 = *(const float4*)&h0[3 * DIM + k4 * 4];
            float4 w0 = *(const float4*)&w[(k4 * 4 + 0) * DIM + c0];
            float4 w1 = *(const float4*)&w[(k4 * 4 + 1) * DIM + c0];
            float4 w2 = *(const float4*)&w[(k4 * 4 + 2) * DIM + c0];
            float4 w3 = *(const float4*)&w[(k4 * 4 + 3) * DIM + c0];
            FMA16(a0, hv0, w0, w1, w2, w3)
            FMA16(a1, hv1, w0, w1, w2, w3)
            FMA16(a2, hv2, w0, w1, w2, w3)
            FMA16(a3, hv3, w0, w1, w2, w3)
        }
        *(float4*)&out[(size_t)r0 * DIM + c0] = a0;
        *(float4*)&out[(size_t)(r0 + 1) * DIM + c0] = a1;
        *(float4*)&out[(size_t)(r0 + 2) * DIM + c0] = a2;
        *(float4*)&out[(size_t)(r0 + 3) * DIM + c0] = a3;
        lsum.x += a0.x + a1.x + a2.x + a3.x;
        lsum.y += a0.y + a1.y + a2.y + a3.y;
        lsum.z += a0.z + a1.z + a2.z + a3.z;
        lsum.w += a0.w + a1.w + a2.w + a3.w;
        lsq.x += a0.x * a0.x + a1.x * a1.x + a2.x * a2.x + a3.x * a3.x;
        lsq.y += a0.y * a0.y + a1.y * a1.y + a2.y * a2.y + a3.y * a3.y;
        lsq.z += a0.z * a0.z + a1.z * a1.z + a2.z * a2.z + a3.z * a3.z;
        lsq.w += a0.w * a0.w + a1.w * a1.w + a2.w * a2.w + a3.w * a3.w;
    }

    *(float4*)&redS[rg * DIM + c0] = lsum;
    *(float4*)&redQ[rg * DIM + c0] = lsq;
    __syncthreads();
    if (threadIdx.x < DIM) {
        float s = 0.f, q = 0.f;
        #pragma unroll
        for (int g = 0; g < 8; ++g) {
            s += redS[g * DIM + threadIdx.x];
            q += redQ[g * DIM + threadIdx.x];
        }
        atomicAdd(&ssum[threadIdx.x], s);
        atomicAdd(&ssq[threadIdx.x], q);
    }
}

// ---------- BN stats finalize ----------
__global__ void k_bnstats(const float* __restrict__ ssum, const float* __restrict__ ssq,
                          const float* __restrict__ gamma, const float* __restrict__ beta,
                          float* __restrict__ scale, float* __restrict__ shift) {
    int c = threadIdx.x;
    float mu = ssum[c] / (float)NN;
    float var = ssq[c] / (float)NN - mu * mu;
    float rs = rsqrtf(var + BN_EPS);
    float sc = rs * gamma[c];
    scale[c] = sc;
    shift[c] = beta[c] - mu * sc;
}

// ---------- BN apply + SELU (in place) ----------
__global__ void k_bnselu(float* __restrict__ h, const float* __restrict__ scale,
                         const float* __restrict__ shift) {
    int i = blockIdx.x * blockDim.x + threadIdx.x;
    if (i >= NN * DIM / 4) return;
    int c0 = (i * 4) & (DIM - 1);
    float4 v = ((float4*)h)[i];
    float4 sc = *(const float4*)&scale[c0];
    float4 sh = *(const float4*)&shift[c0];
    v.x = fmaf(v.x, sc.x, sh.x);
    v.y = fmaf(v.y, sc.y, sh.y);
    v.z = fmaf(v.z, sc.z, sh.z);
    v.w = fmaf(v.w, sc.w, sh.w);
    v.x = v.x > 0.f ? SELU_SCALE * v.x : SELU_SCALE * SELU_ALPHA * (__expf(v.x) - 1.f);
    v.y = v.y > 0.f ? SELU_SCALE * v.y : SELU_SCALE * SELU_ALPHA * (__expf(v.y) - 1.f);
    v.z = v.z > 0.f ? SELU_SCALE * v.z : SELU_SCALE * SELU_ALPHA * (__expf(v.z) - 1.f);
    v.w = v.w > 0.f ? SELU_SCALE * v.w : SELU_SCALE * SELU_ALPHA * (__expf(v.w) - 1.f);
    ((float4*)h)[i] = v;
}

// ---------- GEMM2: t = h1s @ W2 (no bias; bias applied after gather) ----------
// 256 thr: c0=(tid&7)*4 covers 32 cols; rg=tid>>3 -> 32 groups x 4 rows = 128 rows/block.
__global__ __launch_bounds__(256) void k_gemm2(const float* __restrict__ h,
                                               const float* __restrict__ W2,
                                               float* __restrict__ t) {
    __shared__ float w[DIM * NC];
    for (int i = threadIdx.x * 4; i < DIM * NC; i += 1024)
        *(float4*)&w[i] = *(const float4*)&W2[i];
    __syncthreads();

    int c0 = (threadIdx.x & 7) * 4;
    int rg = threadIdx.x >> 3;  // 0..31
    int r0 = blockIdx.x * 128 + rg * 4;
    if (r0 >= NN) return;
    const float* h0 = h + (size_t)r0 * DIM;
    float4 a0 = {0, 0, 0, 0}, a1 = {0, 0, 0, 0}, a2 = {0, 0, 0, 0}, a3 = {0, 0, 0, 0};
    #pragma unroll 4
    for (int k4 = 0; k4 < DIM / 4; ++k4) {
        float4 hv0 = *(const float4*)&h0[k4 * 4];
        float4 hv1 = *(const float4*)&h0[DIM + k4 * 4];
        float4 hv2 = *(const float4*)&h0[2 * DIM + k4 * 4];
        float4 hv3 = *(const float4*)&h0[3 * DIM + k4 * 4];
        float4 w0 = *(const float4*)&w[(k4 * 4 + 0) * NC + c0];
        float4 w1 = *(const float4*)&w[(k4 * 4 + 1) * NC + c0];
        float4 w2 = *(const float4*)&w[(k4 * 4 + 2) * NC + c0];
        float4 w3 = *(const float4*)&w[(k4 * 4 + 3) * NC + c0];
        FMA16(a0, hv0, w0, w1, w2, w3)
        FMA16(a1, hv1, w0, w1, w2, w3)
        FMA16(a2, hv2, w0, w1, w2, w3)
        FMA16(a3, hv3, w0, w1, w2, w3)
    }
    *(float4*)&t[(size_t)r0 * NC + c0] = a0;
    *(float4*)&t[(size_t)(r0 + 1) * NC + c0] = a1;
    *(float4*)&t[(size_t)(r0 + 2) * NC + c0] = a2;
    *(float4*)&t[(size_t)(r0 + 3) * NC + c0] = a3;
}

// ---------- fused gather(32-wide) + bias + softmax ----------
// one wave per node; lane = (half, c); halves split the edge list.
__global__ __launch_bounds__(256) void k_gsoftmax(const float* __restrict__ t,
                                                  const float* __restrict__ b2,
                                                  const int* __restrict__ rowptr,
                                                  const int* __restrict__ eidx,
                                                  float* __restrict__ out) {
    int node = blockIdx.x * 4 + (threadIdx.x >> 6);
    if (node >= NN) return;
    int lane = threadIdx.x & 63;
    int c = lane & 31;
    int half = lane >> 5;
    float acc = half ? 0.f : t[(size_t)node * NC + c];  // self-loop once
    int b = rowptr[node], e = rowptr[node + 1];
    for (int j = b + half; j < e; j += 2)
        acc += t[(size_t)eidx[j] * NC + c];
    acc += __shfl_xor(acc, 32);  // combine halves
    acc += b2[c];
    float m = acc;
    #pragma unroll
    for (int off = 16; off; off >>= 1) m = fmaxf(m, __shfl_xor(m, off, 32));
    float ex = __expf(acc - m);
    float s = ex;
    #pragma unroll
    for (int off = 16; off; off >>= 1) s += __shfl_xor(s, off, 32);
    if (!half) out[(size_t)node * NC + c] = ex / s;
}

extern "C" void kernel_launch(void* const* d_in, const int* in_sizes, int n_in,
                              void* d_out, int out_size, void* d_ws, size_t ws_size,
                              hipStream_t stream) {
    const float* x     = (const float*)d_in[0];
    const void*  eraw  = d_in[1];
    const float* W1    = (const float*)d_in[2];
    const float* b1    = (const float*)d_in[3];
    const float* gamma = (const float*)d_in[4];
    const float* beta  = (const float*)d_in[5];
    const float* W2    = (const float*)d_in[6];
    const float* b2    = (const float*)d_in[7];
    float* out = (float*)d_out;

    // workspace layout (all 16B-aligned)
    float* hA    = (float*)d_ws;                     // NN*DIM
    float* hB    = hA + (size_t)NN * DIM;            // NN*DIM (also reused as t)
    int*   es    = (int*)(hB + (size_t)NN * DIM);    // 2*NE
    int*   eidx  = es + 2 * (size_t)NE;              // NE
    int*   deg   = eidx + NE;                        // NN
    int*   rowptr= deg + NN;                         // NN+4 (padded)
    int*   cursor= rowptr + NN + 4;                  // NN
    int*   bsum  = cursor + NN;                      // 64
    int*   boff  = bsum + 64;                        // 64
    float* ssum  = (float*)(boff + 64);              // DIM
    float* ssq   = ssum + DIM;                       // DIM
    float* scale = ssq + DIM;                        // DIM
    float* shift = scale + DIM;                      // DIM
    int*   flag  = (int*)(shift + DIM);
    int* src = es;
    int* dst = es + NE;
    float* t = hB;

    const int n4 = NN * DIM / 4;

    // edge canonicalization + CSR build
    k_detect<<<1, 64, 0, stream>>>((const int*)eraw, flag);
    k_convert<<<(2 * NE + 255) / 256, 256, 0, stream>>>(eraw, flag, es);
    k_zero_i<<<(NN + 255) / 256, 256, 0, stream>>>(deg, NN);
    k_zero_f<<<1, 256, 0, stream>>>(ssum, 2 * DIM);
    k_hist<<<(NE + 255) / 256, 256, 0, stream>>>(dst, deg);
    k_bsum<<<NSB, 256, 0, stream>>>(deg, bsum);
    k_bscan<<<1, 64, 0, stream>>>(bsum, boff, rowptr);
    k_scanfill<<<NSB, 256, 0, stream>>>(deg, boff, rowptr, cursor);
    k_fill<<<(NE + 255) / 256, 256, 0, stream>>>(src, dst, cursor, eidx);

    const int gather_blocks = (NN + 3) / 4;
    // agg1: hA = x + gather(x)
    k_gather<<<gather_blocks, 256, 0, stream>>>(x, hA, rowptr, eidx);
    // agg2: hB = hA + gather(hA)
    k_gather<<<gather_blocks, 256, 0, stream>>>(hA, hB, rowptr, eidx);
    // gemm1 + BN stats: hA = hB @ W1 + b1
    k_gemm1<<<(NN + 127) / 128, 256, 0, stream>>>(hB, W1, b1, hA, ssum, ssq);
    k_bnstats<<<1, DIM, 0, stream>>>(ssum, ssq, gamma, beta, scale, shift);
    k_bnselu<<<(n4 + 255) / 256, 256, 0, stream>>>(hA, scale, shift);
    // layer 2 reordered: t = h1s @ W2, then out = softmax(gather(t) + b2)
    k_gemm2<<<(NN + 127) / 128, 256, 0, stream>>>(hA, W2, t);
    k_gsoftmax<<<gather_blocks, 256, 0, stream>>>(t, b2, rowptr, eidx, out);
}

// Round 5
// 303.377 us; speedup vs baseline: 13.7076x; 1.1434x over previous
//
#include <hip/hip_runtime.h>

#define NN 50000
#define NE 800000
#define DIM 128
#define NC 32
#define N4 12500          // NN/4 int4 chunks of deg
#define NSB 49            // ceil(N4 / 256) scan blocks
#define BN_EPS 1e-5f
#define SELU_ALPHA 1.6732632423543772f
#define SELU_SCALE 1.0507009873554805f

// acc[c] += sum_i hv[i] * wi[c]
#define FMA16(acc, hv, w0, w1, w2, w3)                                   \
    acc.x = fmaf(hv.x, w0.x, acc.x); acc.y = fmaf(hv.x, w0.y, acc.y);    \
    acc.z = fmaf(hv.x, w0.z, acc.z); acc.w = fmaf(hv.x, w0.w, acc.w);    \
    acc.x = fmaf(hv.y, w1.x, acc.x); acc.y = fmaf(hv.y, w1.y, acc.y);    \
    acc.z = fmaf(hv.y, w1.z, acc.z); acc.w = fmaf(hv.y, w1.w, acc.w);    \
    acc.x = fmaf(hv.z, w2.x, acc.x); acc.y = fmaf(hv.z, w2.y, acc.y);    \
    acc.z = fmaf(hv.z, w2.z, acc.z); acc.w = fmaf(hv.z, w2.w, acc.w);    \
    acc.x = fmaf(hv.w, w3.x, acc.x); acc.y = fmaf(hv.w, w3.y, acc.y);    \
    acc.z = fmaf(hv.w, w3.z, acc.z); acc.w = fmaf(hv.w, w3.w, acc.w);

// ---------- bf16 helpers (packed 2 per uint) ----------
__device__ __forceinline__ float bf_lo(unsigned u) { return __uint_as_float(u << 16); }
__device__ __forceinline__ float bf_hi(unsigned u) { return __uint_as_float(u & 0xffff0000u); }
__device__ __forceinline__ unsigned pack_bf16(float a, float b) {
    unsigned ba = __float_as_uint(a), bb = __float_as_uint(b);
    ba = (ba + 0x7fffu + ((ba >> 16) & 1u)) >> 16;   // round-nearest-even
    bb = (bb + 0x7fffu + ((bb >> 16) & 1u)) >> 16;
    return ba | (bb << 16);
}

// ---------- edge dtype detection + conversion ----------
__global__ void k_detect(const int* __restrict__ raw, int* __restrict__ flag) {
    int v = raw[2 * threadIdx.x + 1];
    unsigned long long b = __ballot(v == 0);
    if (threadIdx.x == 0) *flag = (b == 0xFFFFFFFFFFFFFFFFULL) ? 1 : 0;
}

__global__ void k_convert(const void* __restrict__ raw, const int* __restrict__ flag,
                          int* __restrict__ es) {
    int f = *flag;
    int i = blockIdx.x * blockDim.x + threadIdx.x;
    if (i < 2 * NE) {
        es[i] = f ? (int)((const long long*)raw)[i] : ((const int*)raw)[i];
    }
}

__global__ void k_zero_f(float* __restrict__ p, int n) {
    int i = blockIdx.x * blockDim.x + threadIdx.x;
    if (i < n) p[i] = 0.f;
}

__global__ void k_zero_i(int* __restrict__ p, int n) {
    int i = blockIdx.x * blockDim.x + threadIdx.x;
    if (i < n) p[i] = 0;
}

// ---------- fp32 -> bf16 matrix conversion ----------
__global__ void k_cvt(const float4* __restrict__ in, uint2* __restrict__ out, int n4) {
    int i = blockIdx.x * blockDim.x + threadIdx.x;
    if (i < n4) {
        float4 v = in[i];
        out[i] = make_uint2(pack_bf16(v.x, v.y), pack_bf16(v.z, v.w));
    }
}

// ---------- CSR build (by destination) ----------
__global__ void k_hist(const int* __restrict__ dst, int* __restrict__ deg) {
    int e = blockIdx.x * blockDim.x + threadIdx.x;
    if (e < NE) atomicAdd(&deg[dst[e]], 1);
}

__global__ __launch_bounds__(256) void k_bsum(const int* __restrict__ deg,
                                              int* __restrict__ bsum) {
    int g = blockIdx.x * 256 + threadIdx.x;
    int4 v = {0, 0, 0, 0};
    if (g < N4) v = ((const int4*)deg)[g];
    int s = v.x + v.y + v.z + v.w;
    #pragma unroll
    for (int off = 1; off < 64; off <<= 1) s += __shfl_xor(s, off, 64);
    __shared__ int ws[4];
    if ((threadIdx.x & 63) == 0) ws[threadIdx.x >> 6] = s;
    __syncthreads();
    if (threadIdx.x == 0) bsum[blockIdx.x] = ws[0] + ws[1] + ws[2] + ws[3];
}

__global__ void k_bscan(const int* __restrict__ bsum, int* __restrict__ boff,
                        int* __restrict__ rowptr) {
    int lane = threadIdx.x;  // 64 threads
    int v = (lane < NSB) ? bsum[lane] : 0;
    int inc = v;
    #pragma unroll
    for (int off = 1; off < 64; off <<= 1) {
        int u = __shfl_up(inc, off, 64);
        if (lane >= off) inc += u;
    }
    if (lane < NSB) boff[lane] = inc - v;
    if (lane == 63) rowptr[NN] = inc;  // grand total
}

__global__ __launch_bounds__(256) void k_scanfill(const int* __restrict__ deg,
                                                  const int* __restrict__ boff,
                                                  int* __restrict__ rowptr,
                                                  int* __restrict__ cursor) {
    int g = blockIdx.x * 256 + threadIdx.x;
    int4 v = {0, 0, 0, 0};
    if (g < N4) v = ((const int4*)deg)[g];
    int s = v.x + v.y + v.z + v.w;
    int inc = s;
    int lane = threadIdx.x & 63;
    #pragma unroll
    for (int off = 1; off < 64; off <<= 1) {
        int u = __shfl_up(inc, off, 64);
        if (lane >= off) inc += u;
    }
    __shared__ int wtot[4];
    if (lane == 63) wtot[threadIdx.x >> 6] = inc;
    __syncthreads();
    int wid = threadIdx.x >> 6;
    int pre = 0;
    for (int w = 0; w < wid; ++w) pre += wtot[w];
    int base = boff[blockIdx.x] + pre + (inc - s);
    if (g < N4) {
        int4 r;
        r.x = base;
        r.y = r.x + v.x;
        r.z = r.y + v.y;
        r.w = r.z + v.z;
        ((int4*)rowptr)[g] = r;
        ((int4*)cursor)[g] = r;
    }
}

__global__ void k_fill(const int* __restrict__ src, const int* __restrict__ dst,
                       int* __restrict__ cursor, int* __restrict__ eidx) {
    int e = blockIdx.x * blockDim.x + threadIdx.x;
    if (e < NE) {
        int p = atomicAdd(&cursor[dst[e]], 1);
        eidx[p] = src[e];
    }
}

// ---------- bf16 aggregation: out[i] = in[i] + sum_{j in neigh(i)} in[j] ----------
// one wave per node; lane owns 2 cols via one packed uint. fp32 accumulate.
// OUTBF=1 -> bf16 out (feeds another gather); OUTBF=0 -> fp32 out (feeds GEMM).
template <int OUTBF>
__global__ __launch_bounds__(256) void k_gather_bf(const unsigned* __restrict__ in,
                                                   void* __restrict__ out,
                                                   const int* __restrict__ rowptr,
                                                   const int* __restrict__ eidx) {
    int node = blockIdx.x * 4 + (threadIdx.x >> 6);
    if (node >= NN) return;
    int lane = threadIdx.x & 63;
    unsigned su = in[(size_t)node * 64 + lane];  // self-loop
    float2 acc = {bf_lo(su), bf_hi(su)};
    int b = rowptr[node], e = rowptr[node + 1];
    int j = b;
    for (; j + 3 < e; j += 4) {
        int s0 = eidx[j], s1 = eidx[j + 1], s2 = eidx[j + 2], s3 = eidx[j + 3];
        unsigned u0 = in[(size_t)s0 * 64 + lane];
        unsigned u1 = in[(size_t)s1 * 64 + lane];
        unsigned u2 = in[(size_t)s2 * 64 + lane];
        unsigned u3 = in[(size_t)s3 * 64 + lane];
        acc.x += bf_lo(u0) + bf_lo(u1) + bf_lo(u2) + bf_lo(u3);
        acc.y += bf_hi(u0) + bf_hi(u1) + bf_hi(u2) + bf_hi(u3);
    }
    for (; j < e; ++j) {
        unsigned u0 = in[(size_t)eidx[j] * 64 + lane];
        acc.x += bf_lo(u0);
        acc.y += bf_hi(u0);
    }
    if (OUTBF)
        ((unsigned*)out)[(size_t)node * 64 + lane] = pack_bf16(acc.x, acc.y);
    else
        ((float2*)out)[(size_t)node * 64 + lane] = acc;
}

// ---------- GEMM1 (h @ W1 + b1) + per-column sum/sumsq for BN ----------
__global__ __launch_bounds__(256) void k_gemm1(
    const float* __restrict__ h, const float* __restrict__ W1,
    const float* __restrict__ b1, float* __restrict__ out,
    float* __restrict__ ssum, float* __restrict__ ssq) {
    __shared__ float w[DIM * DIM];
    __shared__ float redS[8 * DIM];
    __shared__ float redQ[8 * DIM];
    for (int i = threadIdx.x * 4; i < DIM * DIM; i += 1024)
        *(float4*)&w[i] = *(const float4*)&W1[i];
    __syncthreads();

    int c0 = (threadIdx.x & 31) * 4;
    int rg = threadIdx.x >> 5;  // 0..7
    float4 bias = *(const float4*)&b1[c0];
    float4 lsum = {0.f, 0.f, 0.f, 0.f};
    float4 lsq  = {0.f, 0.f, 0.f, 0.f};

    for (int pass = 0; pass < 4; ++pass) {
        int r0 = blockIdx.x * 128 + pass * 32 + rg * 4;
        if (r0 >= NN) break;
        const float* h0 = h + (size_t)r0 * DIM;
        float4 a0 = bias, a1 = bias, a2 = bias, a3 = bias;
        #pragma unroll 4
        for (int k4 = 0; k4 < DIM / 4; ++k4) {
            float4 hv0 = *(const float4*)&h0[k4 * 4];
            float4 hv1 = *(const float4*)&h0[DIM + k4 * 4];
            float4 hv2 = *(const float4*)&h0[2 * DIM + k4 * 4];
            float4 hv3 = *(const float4*)&h0[3 * DIM + k4 * 4];
            float4 w0 = *(const float4*)&w[(k4 * 4 + 0) * DIM + c0];
            float4 w1 = *(const float4*)&w[(k4 * 4 + 1) * DIM + c0];
            float4 w2 = *(const float4*)&w[(k4 * 4 + 2) * DIM + c0];
            float4 w3 = *(const float4*)&w[(k4 * 4 + 3) * DIM + c0];
            FMA16(a0, hv0, w0, w1, w2, w3)
            FMA16(a1, hv1, w0, w1, w2, w3)
            FMA16(a2, hv2, w0, w1, w2, w3)
            FMA16(a3, hv3, w0, w1, w2, w3)
        }
        *(float4*)&out[(size_t)r0 * DIM + c0] = a0;
        *(float4*)&out[(size_t)(r0 + 1) * DIM + c0] = a1;
        *(float4*)&out[(size_t)(r0 + 2) * DIM + c0] = a2;
        *(float4*)&out[(size_t)(r0 + 3) * DIM + c0] = a3;
        lsum.x += a0.x + a1.x + a2.x + a3.x;
        lsum.y += a0.y + a1.y + a2.y + a3.y;
        lsum.z += a0.z + a1.z + a2.z + a3.z;
        lsum.w += a0.w + a1.w + a2.w + a3.w;
        lsq.x += a0.x * a0.x + a1.x * a1.x + a2.x * a2.x + a3.x * a3.x;
        lsq.y += a0.y * a0.y + a1.y * a1.y + a2.y * a2.y + a3.y * a3.y;
        lsq.z += a0.z * a0.z + a1.z * a1.z + a2.z * a2.z + a3.z * a3.z;
        lsq.w += a0.w * a0.w + a1.w * a1.w + a2.w * a2.w + a3.w * a3.w;
    }

    *(float4*)&redS[rg * DIM + c0] = lsum;
    *(float4*)&redQ[rg * DIM + c0] = lsq;
    __syncthreads();
    if (threadIdx.x < DIM) {
        float s = 0.f, q = 0.f;
        #pragma unroll
        for (int g = 0; g < 8; ++g) {
            s += redS[g * DIM + threadIdx.x];
            q += redQ[g * DIM + threadIdx.x];
        }
        atomicAdd(&ssum[threadIdx.x], s);
        atomicAdd(&ssq[threadIdx.x], q);
    }
}

// ---------- BN stats finalize ----------
__global__ void k_bnstats(const float* __restrict__ ssum, const float* __restrict__ ssq,
                          const float* __restrict__ gamma, const float* __restrict__ beta,
                          float* __restrict__ scale, float* __restrict__ shift) {
    int c = threadIdx.x;
    float mu = ssum[c] / (float)NN;
    float var = ssq[c] / (float)NN - mu * mu;
    float rs = rsqrtf(var + BN_EPS);
    float sc = rs * gamma[c];
    scale[c] = sc;
    shift[c] = beta[c] - mu * sc;
}

// ---------- BN apply + SELU (in place) ----------
__global__ void k_bnselu(float* __restrict__ h, const float* __restrict__ scale,
                         const float* __restrict__ shift) {
    int i = blockIdx.x * blockDim.x + threadIdx.x;
    if (i >= NN * DIM / 4) return;
    int c0 = (i * 4) & (DIM - 1);
    float4 v = ((float4*)h)[i];
    float4 sc = *(const float4*)&scale[c0];
    float4 sh = *(const float4*)&shift[c0];
    v.x = fmaf(v.x, sc.x, sh.x);
    v.y = fmaf(v.y, sc.y, sh.y);
    v.z = fmaf(v.z, sc.z, sh.z);
    v.w = fmaf(v.w, sc.w, sh.w);
    v.x = v.x > 0.f ? SELU_SCALE * v.x : SELU_SCALE * SELU_ALPHA * (__expf(v.x) - 1.f);
    v.y = v.y > 0.f ? SELU_SCALE * v.y : SELU_SCALE * SELU_ALPHA * (__expf(v.y) - 1.f);
    v.z = v.z > 0.f ? SELU_SCALE * v.z : SELU_SCALE * SELU_ALPHA * (__expf(v.z) - 1.f);
    v.w = v.w > 0.f ? SELU_SCALE * v.w : SELU_SCALE * SELU_ALPHA * (__expf(v.w) - 1.f);
    ((float4*)h)[i] = v;
}

// ---------- GEMM2: t = h1s @ W2 (no bias; bias applied after gather) ----------
__global__ __launch_bounds__(256) void k_gemm2(const float* __restrict__ h,
                                               const float* __restrict__ W2,
                                               float* __restrict__ t) {
    __shared__ float w[DIM * NC];
    for (int i = threadIdx.x * 4; i < DIM * NC; i += 1024)
        *(float4*)&w[i] = *(const float4*)&W2[i];
    __syncthreads();

    int c0 = (threadIdx.x & 7) * 4;
    int rg = threadIdx.x >> 3;  // 0..31
    int r0 = blockIdx.x * 128 + rg * 4;
    if (r0 >= NN) return;
    const float* h0 = h + (size_t)r0 * DIM;
    float4 a0 = {0, 0, 0, 0}, a1 = {0, 0, 0, 0}, a2 = {0, 0, 0, 0}, a3 = {0, 0, 0, 0};
    #pragma unroll 4
    for (int k4 = 0; k4 < DIM / 4; ++k4) {
        float4 hv0 = *(const float4*)&h0[k4 * 4];
        float4 hv1 = *(const float4*)&h0[DIM + k4 * 4];
        float4 hv2 = *(const float4*)&h0[2 * DIM + k4 * 4];
        float4 hv3 = *(const float4*)&h0[3 * DIM + k4 * 4];
        float4 w0 = *(const float4*)&w[(k4 * 4 + 0) * NC + c0];
        float4 w1 = *(const float4*)&w[(k4 * 4 + 1) * NC + c0];
        float4 w2 = *(const float4*)&w[(k4 * 4 + 2) * NC + c0];
        float4 w3 = *(const float4*)&w[(k4 * 4 + 3) * NC + c0];
        FMA16(a0, hv0, w0, w1, w2, w3)
        FMA16(a1, hv1, w0, w1, w2, w3)
        FMA16(a2, hv2, w0, w1, w2, w3)
        FMA16(a3, hv3, w0, w1, w2, w3)
    }
    *(float4*)&t[(size_t)r0 * NC + c0] = a0;
    *(float4*)&t[(size_t)(r0 + 1) * NC + c0] = a1;
    *(float4*)&t[(size_t)(r0 + 2) * NC + c0] = a2;
    *(float4*)&t[(size_t)(r0 + 3) * NC + c0] = a3;
}

// ---------- fused gather(32-wide) + bias + softmax ----------
__global__ __launch_bounds__(256) void k_gsoftmax(const float* __restrict__ t,
                                                  const float* __restrict__ b2,
                                                  const int* __restrict__ rowptr,
                                                  const int* __restrict__ eidx,
                                                  float* __restrict__ out) {
    int node = blockIdx.x * 4 + (threadIdx.x >> 6);
    if (node >= NN) return;
    int lane = threadIdx.x & 63;
    int c = lane & 31;
    int half = lane >> 5;
    float acc = half ? 0.f : t[(size_t)node * NC + c];  // self-loop once
    int b = rowptr[node], e = rowptr[node + 1];
    for (int j = b + half; j < e; j += 2)
        acc += t[(size_t)eidx[j] * NC + c];
    acc += __shfl_xor(acc, 32);  // combine halves
    acc += b2[c];
    float m = acc;
    #pragma unroll
    for (int off = 16; off; off >>= 1) m = fmaxf(m, __shfl_xor(m, off, 32));
    float ex = __expf(acc - m);
    float s = ex;
    #pragma unroll
    for (int off = 16; off; off >>= 1) s += __shfl_xor(s, off, 32);
    if (!half) out[(size_t)node * NC + c] = ex / s;
}

extern "C" void kernel_launch(void* const* d_in, const int* in_sizes, int n_in,
                              void* d_out, int out_size, void* d_ws, size_t ws_size,
                              hipStream_t stream) {
    const float* x     = (const float*)d_in[0];
    const void*  eraw  = d_in[1];
    const float* W1    = (const float*)d_in[2];
    const float* b1    = (const float*)d_in[3];
    const float* gamma = (const float*)d_in[4];
    const float* beta  = (const float*)d_in[5];
    const float* W2    = (const float*)d_in[6];
    const float* b2    = (const float*)d_in[7];
    float* out = (float*)d_out;

    // workspace layout (16B-aligned). Region A (NN*DIM fp32) holds xb+hAb
    // (bf16, 12.8 MB each) early, then is reused as h1 (gemm1 out).
    float*    regA  = (float*)d_ws;                   // NN*DIM fp32 worth
    unsigned* xb    = (unsigned*)regA;                // NN*64 uints (bf16 x)
    unsigned* hAb   = xb + (size_t)NN * 64;           // NN*64 uints (bf16 hA)
    float*    h1    = regA;                           // gemm1 out (overlays xb+hAb)
    float*    hB    = regA + (size_t)NN * DIM;        // NN*DIM fp32 (agg2 out / t)
    int*   es    = (int*)(hB + (size_t)NN * DIM);     // 2*NE
    int*   eidx  = es + 2 * (size_t)NE;               // NE
    int*   deg   = eidx + NE;                         // NN
    int*   rowptr= deg + NN;                          // NN+4 (padded)
    int*   cursor= rowptr + NN + 4;                   // NN
    int*   bsum  = cursor + NN;                       // 64
    int*   boff  = bsum + 64;                         // 64
    float* ssum  = (float*)(boff + 64);               // DIM
    float* ssq   = ssum + DIM;                        // DIM
    float* scale = ssq + DIM;                         // DIM
    float* shift = scale + DIM;                       // DIM
    int*   flag  = (int*)(shift + DIM);
    int* src = es;
    int* dst = es + NE;
    float* t = hB;  // gemm2 out overlays hB (dead after gemm1)

    const int n4 = NN * DIM / 4;

    // edge canonicalization + CSR build
    k_detect<<<1, 64, 0, stream>>>((const int*)eraw, flag);
    k_convert<<<(2 * NE + 255) / 256, 256, 0, stream>>>(eraw, flag, es);
    k_zero_i<<<(NN + 255) / 256, 256, 0, stream>>>(deg, NN);
    k_zero_f<<<1, 256, 0, stream>>>(ssum, 2 * DIM);
    k_hist<<<(NE + 255) / 256, 256, 0, stream>>>(dst, deg);
    k_bsum<<<NSB, 256, 0, stream>>>(deg, bsum);
    k_bscan<<<1, 64, 0, stream>>>(bsum, boff, rowptr);
    k_scanfill<<<NSB, 256, 0, stream>>>(deg, boff, rowptr, cursor);
    k_fill<<<(NE + 255) / 256, 256, 0, stream>>>(src, dst, cursor, eidx);

    // x -> bf16
    k_cvt<<<(n4 + 255) / 256, 256, 0, stream>>>((const float4*)x, (uint2*)xb, n4);

    const int gather_blocks = (NN + 3) / 4;
    // agg1 (bf16 in, bf16 out): hAb = xb + gather(xb)
    k_gather_bf<1><<<gather_blocks, 256, 0, stream>>>(xb, hAb, rowptr, eidx);
    // agg2 (bf16 in, fp32 out): hB = hAb + gather(hAb)
    k_gather_bf<0><<<gather_blocks, 256, 0, stream>>>(hAb, hB, rowptr, eidx);
    // gemm1 + BN stats: h1 = hB @ W1 + b1   (h1 overlays xb/hAb, both dead)
    k_gemm1<<<(NN + 127) / 128, 256, 0, stream>>>(hB, W1, b1, h1, ssum, ssq);
    k_bnstats<<<1, DIM, 0, stream>>>(ssum, ssq, gamma, beta, scale, shift);
    k_bnselu<<<(n4 + 255) / 256, 256, 0, stream>>>(h1, scale, shift);
    // layer 2 reordered: t = h1s @ W2, then out = softmax(gather(t) + b2)
    k_gemm2<<<(NN + 127) / 128, 256, 0, stream>>>(h1, W2, t);
    k_gsoftmax<<<gather_blocks, 256, 0, stream>>>(t, b2, rowptr, eidx, out);
}